// Round 4
// baseline (840.978 us; speedup 1.0000x reference)
//
#include <hip/hip_runtime.h>

// Elman RNN via MFMA, register-chained recurrence.
//   H^T_{t+1} = tanh(W_hh * H^T_t + W_ih * x_t^T + b),  out = sigmoid(fc_w . h_T + fc_b)
//
// mfma_f32_16x16x16f16 layout facts used:
//   A[m][k]: m = lane&15, k = (lane>>4)*4 + i   (4 halves/lane)
//   B[k][n]: k = (lane>>4)*4 + i, n = lane&15   (4 halves/lane)
//   D[m][n]: n = lane&15, m = (lane>>4)*4 + reg (4 f32/lane)
// => D regs of m-tile mt are EXACTLY the B-frag of k-tile kt=mt for the next
//    step (same lane, element i = reg). The recurrence never leaves registers.
//
// One wave = 16 samples (matrix cols) x all 64 hidden (4 m-tiles).
// 128 waves total; W_hh lives in 16 A-frags (32 VGPRs) per lane.

#define RN 2048
#define RT 512
#define RI 32
#define RH 64

typedef _Float16 h4 __attribute__((ext_vector_type(4)));
typedef float    f4 __attribute__((ext_vector_type(4)));

__device__ __forceinline__ int pk2(float a, float b) {
    return __builtin_bit_cast(int, __builtin_amdgcn_cvt_pkrtz(a, b));
}
__device__ __forceinline__ h4 pack4(float a, float b, float c, float d) {
    union { h4 v; int i[2]; } u;
    u.i[0] = pk2(a, b);
    u.i[1] = pk2(c, d);
    return u.v;
}
__device__ __forceinline__ h4 packf4(f4 v) { return pack4(v[0], v[1], v[2], v[3]); }

__device__ __forceinline__ float tanh_fast(float z) {
    // 1 - 2/(e^{2z}+1); exact saturation at +/-inf
    float e = __expf(2.0f * z);
    return 1.0f - __fdividef(2.0f, e + 1.0f);
}

__global__ __launch_bounds__(64, 1) void rnn_mfma(
    const float* __restrict__ x,
    const float* __restrict__ W_ih,
    const float* __restrict__ W_hh,
    const float* __restrict__ b_ih,
    const float* __restrict__ b_hh,
    const float* __restrict__ fc_w,
    const float* __restrict__ fc_b,
    float* __restrict__ out)
{
    const int l    = threadIdx.x;
    const int col  = l & 15;   // sample within group / matrix col
    const int quad = l >> 4;   // 0..3
    const int g    = blockIdx.x;

    // ---- W_hh A-frags: Ahh[mt][kt] = W_hh[mt*16+col][kt*16+quad*4 + i] ----
    h4 Ahh[4][4];
#pragma unroll
    for (int mt = 0; mt < 4; ++mt)
#pragma unroll
        for (int kt = 0; kt < 4; ++kt) {
            f4 w = *(const f4*)(W_hh + (mt * 16 + col) * RH + kt * 16 + quad * 4);
            Ahh[mt][kt] = packf4(w);
        }
    // ---- W_ih A-frags (K=32 as two K=16 tiles) ----
    h4 Aih[4][2];
#pragma unroll
    for (int mt = 0; mt < 4; ++mt)
#pragma unroll
        for (int kt = 0; kt < 2; ++kt) {
            f4 w = *(const f4*)(W_ih + (mt * 16 + col) * RI + kt * 16 + quad * 4);
            Aih[mt][kt] = packf4(w);
        }
    // ---- bias in D layout: biasv[mt][r] = b[mt*16 + quad*4 + r] ----
    f4 biasv[4];
#pragma unroll
    for (int mt = 0; mt < 4; ++mt) {
        f4 bi = *(const f4*)(b_ih + mt * 16 + quad * 4);
        f4 bh = *(const f4*)(b_hh + mt * 16 + quad * 4);
        biasv[mt] = bi + bh;
    }

    // ---- x stream for this lane's sample, 2-step prefetch depth ----
    const float* xb = x + (size_t)(g * 16 + col) * (RT * RI);
    f4 xbuf[2][2];
#pragma unroll
    for (int t = 0; t < 2; ++t)
#pragma unroll
        for (int kt = 0; kt < 2; ++kt)
            xbuf[t][kt] = *(const f4*)(xb + t * RI + kt * 16 + quad * 4);

    // ---- h0 = ones, already in B-frag layout ----
    h4 Bh[4];
#pragma unroll
    for (int kt = 0; kt < 4; ++kt) Bh[kt] = pack4(1.f, 1.f, 1.f, 1.f);
    f4 hf[4]; // f32 copy of current h (D layout) for the epilogue

    for (int t = 0; t < RT; ++t) {
        const int p = t & 1;
        h4 bx0 = packf4(xbuf[p][0]);
        h4 bx1 = packf4(xbuf[p][1]);
        int tn = t + 2; if (tn > RT - 1) tn = RT - 1;
        xbuf[p][0] = *(const f4*)(xb + tn * RI + quad * 4);
        xbuf[p][1] = *(const f4*)(xb + tn * RI + 16 + quad * 4);

        f4 acc[4];
#pragma unroll
        for (int mt = 0; mt < 4; ++mt) {
            f4 a = biasv[mt];
            a = __builtin_amdgcn_mfma_f32_16x16x16f16(Aih[mt][0], bx0, a, 0, 0, 0);
            a = __builtin_amdgcn_mfma_f32_16x16x16f16(Aih[mt][1], bx1, a, 0, 0, 0);
#pragma unroll
            for (int kt = 0; kt < 4; ++kt)
                a = __builtin_amdgcn_mfma_f32_16x16x16f16(Ahh[mt][kt], Bh[kt], a, 0, 0, 0);
            acc[mt] = a;
        }
#pragma unroll
        for (int mt = 0; mt < 4; ++mt) {
            f4 hv;
            hv[0] = tanh_fast(acc[mt][0]);
            hv[1] = tanh_fast(acc[mt][1]);
            hv[2] = tanh_fast(acc[mt][2]);
            hv[3] = tanh_fast(acc[mt][3]);
            hf[mt] = hv;
        }
#pragma unroll
        for (int mt = 0; mt < 4; ++mt)
            Bh[mt] = packf4(hf[mt]); // D m-tile mt -> B k-tile mt
    }

    // ---- epilogue: out[n] = sigmoid(sum_j fc_w[j] h[n][j] + fc_b) ----
    float s = 0.f;
#pragma unroll
    for (int mt = 0; mt < 4; ++mt) {
        f4 w = *(const f4*)(fc_w + mt * 16 + quad * 4);
        s += w[0] * hf[mt][0] + w[1] * hf[mt][1] + w[2] * hf[mt][2] + w[3] * hf[mt][3];
    }
    s += __shfl_xor(s, 16, 64);
    s += __shfl_xor(s, 32, 64);
    if (quad == 0) {
        float logit = s + fc_b[0];
        out[g * 16 + col] = __fdividef(1.0f, 1.0f + __expf(-logit));
    }
}

extern "C" void kernel_launch(void* const* d_in, const int* in_sizes, int n_in,
                              void* d_out, int out_size, void* d_ws, size_t ws_size,
                              hipStream_t stream) {
    rnn_mfma<<<RN / 16, 64, 0, stream>>>(
        (const float*)d_in[0], (const float*)d_in[1], (const float*)d_in[2],
        (const float*)d_in[3], (const float*)d_in[4], (const float*)d_in[5],
        (const float*)d_in[6], (float*)d_out);
}

// Round 5
// 309.590 us; speedup vs baseline: 2.7164x; 2.7164x over previous
//
#include <hip/hip_runtime.h>

// Elman RNN via MFMA, register-chained recurrence, j-split across 4 waves.
//   H^T_{t+1} = tanh(W_hh * H^T_t + W_ih * x_t^T + b),  out = sigmoid(fc_w.h_T + fc_b)
//
// mfma_f32_16x16x16f16 layouts (HW-verified in round 4, absmax 3.9e-3):
//   A[m][k]: m = lane&15, k = quad*4 + i
//   B[k][n]: k = quad*4 + i, n = lane&15
//   D[m][n]: n = lane&15, m = quad*4 + reg
// => a wave's D tile (m-tile mt), packed to fp16, IS the B-frag of k-tile
//    kt = mt for the next step, in the same lane. Waves exchange their 8 B
//    frags through LDS (double-buffered, ONE barrier/step).
//
// WG = 4 waves = 16 samples; wave w owns m-tile w (hidden units w*16..w*16+15).
// Per wave per step: 6 MFMAs (two 3-deep chains), 4 tanh, 2 pkrtz, 1 ds_write_b64,
// 4 ds_read_b64, 1 barrier. 128 WGs -> 512 waves on 128 CUs.

#define RN 2048
#define RT 512
#define RI 32
#define RH 64

typedef _Float16 h4 __attribute__((ext_vector_type(4)));
typedef float    f4 __attribute__((ext_vector_type(4)));

__device__ __forceinline__ int pk2(float a, float b) {
    return __builtin_bit_cast(int, __builtin_amdgcn_cvt_pkrtz(a, b));
}
__device__ __forceinline__ h4 pack4(float a, float b, float c, float d) {
    union { h4 v; int i[2]; } u;
    u.i[0] = pk2(a, b);
    u.i[1] = pk2(c, d);
    return u.v;
}
__device__ __forceinline__ h4 packf4(f4 v) { return pack4(v[0], v[1], v[2], v[3]); }

__device__ __forceinline__ float tanh_fast(float z) {
    // 1 - 2/(e^{2z}+1); exact saturation for large |z|
    float e = __expf(2.0f * z);
    return 1.0f - __fdividef(2.0f, e + 1.0f);
}

__global__ __launch_bounds__(256, 1) void rnn_mfma4(
    const float* __restrict__ x,
    const float* __restrict__ W_ih,
    const float* __restrict__ W_hh,
    const float* __restrict__ b_ih,
    const float* __restrict__ b_hh,
    const float* __restrict__ fc_w,
    const float* __restrict__ fc_b,
    float* __restrict__ out)
{
    const int tid  = threadIdx.x;
    const int w    = tid >> 6;      // wave id = m-tile
    const int lane = tid & 63;
    const int col  = lane & 15;     // sample within group
    const int quad = lane >> 4;     // 0..3
    const int g    = blockIdx.x;

    // h exchange: [buf][kt*64 + lane] -> 8 B B-frag. 2-way bank alias only.
    __shared__ unsigned long long hb[2][4 * 64];
    __shared__ float ob[4][16];

    // ---- A-frags for my m-tile ----
    h4 Ahh[4];
#pragma unroll
    for (int kt = 0; kt < 4; ++kt) {
        f4 v = *(const f4*)(W_hh + (w * 16 + col) * RH + kt * 16 + quad * 4);
        Ahh[kt] = packf4(v);
    }
    h4 Aih[2];
#pragma unroll
    for (int kt = 0; kt < 2; ++kt) {
        f4 v = *(const f4*)(W_ih + (w * 16 + col) * RI + kt * 16 + quad * 4);
        Aih[kt] = packf4(v);
    }
    f4 biasv;
    {
        f4 bi = *(const f4*)(b_ih + w * 16 + quad * 4);
        f4 bh = *(const f4*)(b_hh + w * 16 + quad * 4);
        biasv = bi + bh;
    }

    // ---- x stream for this lane's sample, 4-step static ring ----
    const float* xb = x + (size_t)(g * 16 + col) * (RT * RI);
    f4 xbuf[4][2];
#pragma unroll
    for (int s = 0; s < 4; ++s) {
        xbuf[s][0] = *(const f4*)(xb + s * RI + quad * 4);
        xbuf[s][1] = *(const f4*)(xb + s * RI + 16 + quad * 4);
    }

    // h0 = ones, already in B-frag layout
    h4 Bh[4];
#pragma unroll
    for (int kt = 0; kt < 4; ++kt) Bh[kt] = pack4(1.f, 1.f, 1.f, 1.f);
    f4 hv; // f32 h of final step (my m-tile rows), for epilogue

    for (int t4 = 0; t4 < RT; t4 += 4) {
#pragma unroll
        for (int s = 0; s < 4; ++s) {
            const int t = t4 + s;
            h4 bx0 = packf4(xbuf[s][0]);
            h4 bx1 = packf4(xbuf[s][1]);
            int tn = t + 4; if (tn > RT - 1) tn = RT - 1;
            xbuf[s][0] = *(const f4*)(xb + tn * RI + quad * 4);
            xbuf[s][1] = *(const f4*)(xb + tn * RI + 16 + quad * 4);

            // two balanced 3-deep MFMA chains; x-part is independent of Bh,
            // so it issues while the ds_read of h is still in flight.
            f4 c0 = __builtin_amdgcn_mfma_f32_16x16x16f16(Aih[0], bx0, biasv, 0, 0, 0);
            f4 c1 = __builtin_amdgcn_mfma_f32_16x16x16f16(Aih[1], bx1, f4{0.f, 0.f, 0.f, 0.f}, 0, 0, 0);
            c0 = __builtin_amdgcn_mfma_f32_16x16x16f16(Ahh[0], Bh[0], c0, 0, 0, 0);
            c1 = __builtin_amdgcn_mfma_f32_16x16x16f16(Ahh[1], Bh[1], c1, 0, 0, 0);
            c0 = __builtin_amdgcn_mfma_f32_16x16x16f16(Ahh[2], Bh[2], c0, 0, 0, 0);
            c1 = __builtin_amdgcn_mfma_f32_16x16x16f16(Ahh[3], Bh[3], c1, 0, 0, 0);
            f4 acc = c0 + c1;

            hv[0] = tanh_fast(acc[0]);
            hv[1] = tanh_fast(acc[1]);
            hv[2] = tanh_fast(acc[2]);
            hv[3] = tanh_fast(acc[3]);

            // publish my D tile as next step's B-frag kt = w
            const int p = t & 1;
            hb[p][w * 64 + lane] = __builtin_bit_cast(unsigned long long, packf4(hv));
            __syncthreads();
            Bh[0] = __builtin_bit_cast(h4, hb[p][0 * 64 + lane]);
            Bh[1] = __builtin_bit_cast(h4, hb[p][1 * 64 + lane]);
            Bh[2] = __builtin_bit_cast(h4, hb[p][2 * 64 + lane]);
            Bh[3] = __builtin_bit_cast(h4, hb[p][3 * 64 + lane]);
        }
    }

    // ---- epilogue: out[n] = sigmoid(sum_j fc_w[j] h[n][j] + fc_b) ----
    {
        f4 wv = *(const f4*)(fc_w + w * 16 + quad * 4);
        float s = wv[0] * hv[0] + wv[1] * hv[1] + wv[2] * hv[2] + wv[3] * hv[3];
        s += __shfl_xor(s, 16, 64);
        s += __shfl_xor(s, 32, 64); // all lanes: partial over my 16 hidden units
        if (quad == 0) ob[w][col] = s;
        __syncthreads();
        if (w == 0 && lane < 16) {
            float logit = ob[0][lane] + ob[1][lane] + ob[2][lane] + ob[3][lane] + fc_b[0];
            out[g * 16 + lane] = __fdividef(1.0f, 1.0f + __expf(-logit));
        }
    }
}

extern "C" void kernel_launch(void* const* d_in, const int* in_sizes, int n_in,
                              void* d_out, int out_size, void* d_ws, size_t ws_size,
                              hipStream_t stream) {
    rnn_mfma4<<<RN / 16, 256, 0, stream>>>(
        (const float*)d_in[0], (const float*)d_in[1], (const float*)d_in[2],
        (const float*)d_in[3], (const float*)d_in[4], (const float*)d_in[5],
        (const float*)d_in[6], (float*)d_out);
}